// Round 10
// baseline (13466.234 us; speedup 1.0000x reference)
//
#include <hip/hip_runtime.h>
#include <math.h>

#define N 8192
#define DIM 64
#define CAP_E 2000000

typedef unsigned long long u64;
typedef unsigned int u32;
typedef unsigned short u16;

// ---------------- zero the output buffer (births stay 0) -----------------------
__global__ void zero_out_kernel(float* __restrict__ out, int n) {
    int i = blockIdx.x * blockDim.x + threadIdx.x;
    if (i < n) out[i] = 0.0f;
}

// ---------------- canonical norms: ni = sum fmaf(x_k, x_k) ascending k ---------
__global__ __launch_bounds__(256) void norms_kernel(const float* __restrict__ x,
                                                    float* __restrict__ norms) {
    int i = blockIdx.x * blockDim.x + threadIdx.x;
    const float* row = x + (size_t)i * DIM;
    float acc = 0.f;
    #pragma unroll
    for (int k = 0; k < DIM; k++) { float v = row[k]; acc = __builtin_fmaf(v, v, acc); }
    norms[i] = acc;
}

// ---------------- canonical tile machinery (FROZEN — matches R6 bitwise) -------
__device__ inline void stage_tiles(const float* __restrict__ x, int bi, int bj, int t,
                                   float (*As)[64], float (*Bs)[64]) {
    int r = t >> 2, c0 = (t & 3) * 16;
    const float4* pa = (const float4*)(x + (size_t)(bi * 64 + r) * DIM + c0);
    const float4* pb = (const float4*)(x + (size_t)(bj * 64 + r) * DIM + c0);
    #pragma unroll
    for (int q = 0; q < 4; q++) {
        float4 a = pa[q], b = pb[q];
        int c = c0 + q * 4;
        As[c + 0][r] = a.x; As[c + 1][r] = a.y; As[c + 2][r] = a.z; As[c + 3][r] = a.w;
        Bs[c + 0][r] = b.x; Bs[c + 1][r] = b.y; Bs[c + 2][r] = b.z; Bs[c + 3][r] = b.w;
    }
}

__device__ inline void tile_d2(const float (*As)[64], const float (*Bs)[64],
                               const float ni[4], const float nj[4],
                               int tx, int ty, u32 d2b[4][4]) {
    float acc[4][4] = {};
    #pragma unroll 4
    for (int k = 0; k < 64; k++) {
        float av[4], bv[4];
        #pragma unroll
        for (int r = 0; r < 4; r++) av[r] = As[k][ty * 4 + r];
        #pragma unroll
        for (int c = 0; c < 4; c++) bv[c] = Bs[k][tx * 4 + c];
        #pragma unroll
        for (int r = 0; r < 4; r++)
            #pragma unroll
            for (int c = 0; c < 4; c++)
                acc[r][c] = __builtin_fmaf(av[r], bv[c], acc[r][c]);
    }
    #pragma unroll
    for (int r = 0; r < 4; r++)
        #pragma unroll
        for (int c = 0; c < 4; c++) {
            float d2 = __builtin_fmaf(-2.0f, acc[r][c], ni[r] + nj[c]);
            d2 = d2 < 0.f ? 0.f : d2;
            d2b[r][c] = __float_as_uint(d2);
        }
}

// ---------------- init ---------------------------------------------------------
// ctr[0]=mstCount ctr[1]=done ctr[2]=flag ctr[3]=edgeCount ctr[7]=dummy
__global__ void init_kernel(u64* bestR, u64* bestC, u16* comp16, u32* deg, u32* ctr) {
    int i = blockIdx.x * blockDim.x + threadIdx.x;
    if (i < 8192) { bestR[i] = ~0ull; bestC[i] = ~0ull; comp16[i] = (u16)i; deg[i] = 0; }
    if (i < 8) ctr[i] = 0;
}

__device__ inline u64 shfl_down_u64(u64 p, int off) {
    unsigned hi = (unsigned)(p >> 32), lo = (unsigned)p;
    hi = __shfl_down(hi, off, 64);
    lo = __shfl_down(lo, off, 64);
    return ((u64)hi << 32) | lo;
}

// ---------------- Boruvka fused scan (unchanged from R6) -----------------------
__global__ __launch_bounds__(256) void scan_fused(const float* __restrict__ x,
                                                  const float* __restrict__ norms,
                                                  const u16* __restrict__ comp16,
                                                  u64* __restrict__ bestR,
                                                  const u32* __restrict__ ctr) {
    if (ctr[1]) return;
    int bi = blockIdx.y, bj = blockIdx.x;
    if (bj < bi) return;
    __shared__ float As[64][64], Bs[64][64];
    __shared__ u16 rc[64], cc[64];
    __shared__ u64 rowBest[64], colBest[64];
    int t = threadIdx.x;
    stage_tiles(x, bi, bj, t, As, Bs);
    if (t < 64) {
        rc[t] = comp16[bi * 64 + t];
        cc[t] = comp16[bj * 64 + t];
        rowBest[t] = ~0ull; colBest[t] = ~0ull;
    }
    __syncthreads();
    int tx = t & 15, ty = t >> 4;
    float ni[4], nj[4];
    #pragma unroll
    for (int r = 0; r < 4; r++) ni[r] = norms[bi * 64 + ty * 4 + r];
    #pragma unroll
    for (int c = 0; c < 4; c++) nj[c] = norms[bj * 64 + tx * 4 + c];
    u32 d2b[4][4];
    tile_d2(As, Bs, ni, nj, tx, ty, d2b);

    #pragma unroll
    for (int r = 0; r < 4; r++) {
        u16 rcv = rc[ty * 4 + r];
        int gi = bi * 64 + ty * 4 + r;
        u64 best = ~0ull;
        #pragma unroll
        for (int c = 0; c < 4; c++) {
            if (cc[tx * 4 + c] != rcv) {
                int gj = bj * 64 + tx * 4 + c;
                u32 lo = gi < gj ? (u32)gi : (u32)gj;
                u32 hi = gi < gj ? (u32)gj : (u32)gi;
                u64 key = ((u64)d2b[r][c] << 26) | ((u64)lo << 13) | hi;
                if (key < best) best = key;
            }
        }
        if (best != ~0ull) atomicMin(&rowBest[ty * 4 + r], best);
    }
    #pragma unroll
    for (int c = 0; c < 4; c++) {
        u16 ccv = cc[tx * 4 + c];
        int gj = bj * 64 + tx * 4 + c;
        u64 best = ~0ull;
        #pragma unroll
        for (int r = 0; r < 4; r++) {
            if (rc[ty * 4 + r] != ccv) {
                int gi = bi * 64 + ty * 4 + r;
                u32 lo = gi < gj ? (u32)gi : (u32)gj;
                u32 hi = gi < gj ? (u32)gj : (u32)gi;
                u64 key = ((u64)d2b[r][c] << 26) | ((u64)lo << 13) | hi;
                if (key < best) best = key;
            }
        }
        if (best != ~0ull) atomicMin(&colBest[tx * 4 + c], best);
    }
    __syncthreads();
    if (t < 64) {
        if (rowBest[t] != ~0ull) atomicMin(&bestR[bi * 64 + t], rowBest[t]);
        if (colBest[t] != ~0ull) atomicMin(&bestR[bj * 64 + t], colBest[t]);
    }
}

// ---------------- fold rows -> components --------------------------------------
__global__ void fold_kernel(u64* bestR, u64* bestC, const u16* comp16, const u32* ctr) {
    if (ctr[1]) return;
    int i = blockIdx.x * blockDim.x + threadIdx.x;
    if (i < 8192) {
        u64 k = bestR[i];
        if (k != ~0ull) { atomicMin(&bestC[comp16[i]], k); bestR[i] = ~0ull; }
    }
}

// ---------------- Boruvka merge (unchanged) ------------------------------------
__global__ __launch_bounds__(1024) void merge_kernel(u16* comp16, u64* bestC,
                                                     u64* mstKeys, u32* ctr) {
    __shared__ u16 ping[8192], pong[8192];
    __shared__ unsigned char act[8192];
    __shared__ u32 cnt_s;
    if (ctr[1]) return;
    int t = threadIdx.x;
    if (t == 0) cnt_s = 0;
    for (int c = t; c < 8192; c += 1024) {
        u64 key = bestC[c];
        u16 par = (u16)c;
        if (key != ~0ull) {
            u32 a = (u32)(key >> 13) & 8191u, b = (u32)key & 8191u;
            u16 ca = comp16[a];
            u16 cv = (ca == (u16)c) ? comp16[b] : ca;
            u64 k2 = bestC[cv];
            bool mutual = false;
            if (k2 != ~0ull) {
                u32 a2 = (u32)(k2 >> 13) & 8191u, b2 = (u32)k2 & 8191u;
                u16 ca2 = comp16[a2];
                u16 cv2 = (ca2 == cv) ? comp16[b2] : ca2;
                mutual = (cv2 == (u16)c);
            }
            par = cv;
            if (mutual && (u32)c < (u32)cv) par = (u16)c;
            bool add = (!mutual) || ((u32)c < (u32)cv);
            if (add) {
                u32 idx = atomicAdd(&ctr[0], 1u);
                if (idx < 8192u) mstKeys[idx] = key;
            }
        }
        ping[c] = par;
        act[c] = 0;
    }
    __syncthreads();
    for (int c = t; c < 8192; c += 1024) bestC[c] = ~0ull;
    __syncthreads();
    for (int it = 0; it < 13; it++) {
        for (int c = t; c < 8192; c += 1024) pong[c] = ping[ping[c]];
        __syncthreads();
        for (int c = t; c < 8192; c += 1024) ping[c] = pong[c];
        __syncthreads();
    }
    for (int v = t; v < 8192; v += 1024) {
        u16 nc = ping[comp16[v]];
        comp16[v] = nc;
        act[nc] = 1;
    }
    __syncthreads();
    u32 local = 0;
    for (int c = t; c < 8192; c += 1024) local += act[c];
    atomicAdd(&cnt_s, local);
    __syncthreads();
    if (t == 0 && cnt_s == 1) ctr[1] = 1;
}

// ---------------- bitonic sort -> sorted d2 bit-patterns (unchanged) -----------
__global__ __launch_bounds__(1024) void sort_kernel(const u64* __restrict__ mstKeys,
                                                    u32* __restrict__ sortedWB,
                                                    const u32* __restrict__ ctr) {
    __shared__ u64 keys[8192];
    int t = threadIdx.x;
    u32 m = ctr[0]; if (m > 8191u) m = 8191u;
    for (int i = t; i < 8192; i += 1024) keys[i] = (i < (int)m) ? mstKeys[i] : ~0ull;
    __syncthreads();
    for (u32 k = 2; k <= 8192; k <<= 1)
        for (u32 j = k >> 1; j > 0; j >>= 1) {
            for (int i = t; i < 8192; i += 1024) {
                u32 ixj = (u32)i ^ j;
                if (ixj > (u32)i) {
                    u64 a = keys[i], b = keys[ixj];
                    bool up = ((i & k) == 0);
                    if ((a > b) == up) { keys[i] = b; keys[ixj] = a; }
                }
            }
            __syncthreads();
        }
    for (int i = t; i < 8192; i += 1024)
        sortedWB[i] = (i < 8191) ? (u32)(keys[i] >> 26) : 0xFFFFFFFFu;
}

// ---------------- collect G' (unchanged; rank = lower_bound index) -------------
__global__ __launch_bounds__(256) void collect_kernel(const float* __restrict__ x,
                                                      const float* __restrict__ norms,
                                                      const u32* __restrict__ sortedWB,
                                                      u64* __restrict__ edges,
                                                      u32* __restrict__ ctr) {
    __shared__ float As[64][64], Bs[64][64];
    __shared__ u32 sw[8191];
    int bi = blockIdx.y, bj = blockIdx.x;
    if (bj < bi) return;
    int t = threadIdx.x;
    stage_tiles(x, bi, bj, t, As, Bs);
    for (int i = t; i < 8191; i += 256) sw[i] = sortedWB[i];
    __syncthreads();
    u32 wmin = sw[0], wmax = sw[8190];
    int tx = t & 15, ty = t >> 4;
    float ni[4], nj[4];
    #pragma unroll
    for (int r = 0; r < 4; r++) ni[r] = norms[bi * 64 + ty * 4 + r];
    #pragma unroll
    for (int c = 0; c < 4; c++) nj[c] = norms[bj * 64 + tx * 4 + c];
    u32 d2b[4][4];
    tile_d2(As, Bs, ni, nj, tx, ty, d2b);

    #pragma unroll
    for (int r = 0; r < 4; r++) {
        int gi = bi * 64 + ty * 4 + r;
        #pragma unroll
        for (int c = 0; c < 4; c++) {
            int gj = bj * 64 + tx * 4 + c;
            if (gj <= gi) continue;
            u32 wb = d2b[r][c];
            if (wb < wmin || wb > wmax) continue;
            int lo = 0, hi = 8190;
            while (lo < hi) { int mid = (lo + hi) >> 1; if (sw[mid] < wb) lo = mid + 1; else hi = mid; }
            if (sw[lo] == wb) {
                u32 idx = atomicAdd(&ctr[3], 1u);
                if (idx < CAP_E)
                    edges[idx] = ((u64)(u32)lo << 26) | ((u64)(u32)gi << 13) | (u32)gj;
                else
                    atomicOr(&ctr[2], 16u);
            }
        }
    }
}

// ---------------- degree count (R6) --------------------------------------------
__global__ void degcnt_kernel(const u64* __restrict__ edges, u32* __restrict__ deg,
                              const u32* __restrict__ ctr) {
    u32 m = ctr[3]; if (m > CAP_E) m = CAP_E;
    for (u32 idx = blockIdx.x * 256u + threadIdx.x; idx < m; idx += gridDim.x * 256u) {
        u64 e = edges[idx];
        atomicAdd(&deg[(u32)(e >> 13) & 8191u], 1u);
        atomicAdd(&deg[(u32)e & 8191u], 1u);
    }
}

// ---------------- prefix sum: offs[8193] + cur (R6) ----------------------------
__global__ __launch_bounds__(1024) void offs_kernel(const u32* __restrict__ deg,
                                                    u32* __restrict__ offs,
                                                    u32* __restrict__ cur) {
    __shared__ u32 partial[1024];
    int t = threadIdx.x;
    u32 loc[8], s = 0;
    #pragma unroll
    for (int e = 0; e < 8; e++) { loc[e] = deg[t * 8 + e]; s += loc[e]; }
    partial[t] = s;
    __syncthreads();
    for (int d = 1; d < 1024; d <<= 1) {
        u32 v = (t >= d) ? partial[t - d] : 0;
        __syncthreads();
        partial[t] += v;
        __syncthreads();
    }
    u32 run = t ? partial[t - 1] : 0;
    #pragma unroll
    for (int e = 0; e < 8; e++) { offs[t * 8 + e] = run; cur[t * 8 + e] = run; run += loc[e]; }
    if (t == 1023) offs[8192] = run;
}

// ---------------- fill CSR adjacency: entry = rank(13)<<13 | far(13) (R6) ------
__global__ void fill_kernel(const u64* __restrict__ edges, u32* __restrict__ cur,
                            u32* __restrict__ adj, const u32* __restrict__ ctr) {
    u32 m = ctr[3]; if (m > CAP_E) m = CAP_E;
    for (u32 idx = blockIdx.x * 256u + threadIdx.x; idx < m; idx += gridDim.x * 256u) {
        u64 e = edges[idx];
        u32 rk = (u32)(e >> 26) & 8191u;
        u32 i = (u32)(e >> 13) & 8191u, j = (u32)e & 8191u;
        u32 p1 = atomicAdd(&cur[i], 1u); adj[p1] = (rk << 13) | j;
        u32 p2 = atomicAdd(&cur[j], 1u); adj[p2] = (rk << 13) | i;
    }
}

// ---------------- exact sparse Prim on G' — R6 semantics + 3 latency opts ------
// R6-proven invariants: owner-only sMind writes (vertex u owned by lane u&63),
// owner-only cmin maintenance, full rescan of popped vertex's row, serial
// broadcast apply of staged entries, shfl_down+broadcast reduces ONLY.
// New (semantics-preserving): L2 warm pass; sOffs+first-chunk load hoisted
// above the rescan; scratch consumed via b128 broadcast reads (16 entries per
// LDS latency instead of 1).
__global__ __launch_bounds__(64) void gprim_kernel(const u32* __restrict__ offs,
                                                   const u32* __restrict__ adjG,
                                                   u32* __restrict__ seqv,
                                                   u32* __restrict__ ctr) {
    __shared__ u16 sMind[8192];   // vertex v -> sMind[(v&63)*128 + (v>>6)], 0xFFFF = inf
    __shared__ u32 sOffs[8193];
    __shared__ __align__(16) u32 scratch[64];
    const int lane = threadIdx.x;
    for (int i = lane; i < 8192; i += 64) sMind[i] = 0xFFFF;
    for (int i = lane; i < 8193; i += 64) sOffs[i] = offs[i];
    __syncthreads();

    // warm adj (512 KB window) into this XCD's L2 — read-only, no side effects
    {
        u32 acc = 0;
        const uint4* p4 = (const uint4*)adjG;
        for (int i = lane; i < 32768; i += 64) {
            uint4 q = p4[i];
            acc ^= q.x ^ q.y ^ q.z ^ q.w;
        }
        if (acc == 0xDEADBEEFu) atomicAdd(&ctr[7], 1u);   // keep loads alive
    }

    const u32 INFP = 0xFFFFu << 13;
    u64 ins0 = 0, ins1 = 0;            // inserted bits for this lane's 128 slots
    u32 cmin = 0xFFFFFFFFu;
    u32 v = 0;

    for (int step = 0; step < N - 1; ++step) {
        const int L = (int)(v & 63u);
        u32 o = sOffs[v], oe = sOffs[v + 1];
        u32 dg = oe - o;
        // issue first-chunk adjacency load early (overlaps the rescan below)
        u32 kk = o + (u32)lane;
        u32 ev0 = 0xFFFFFFFFu;
        if (kk < oe) ev0 = adjG[kk];
        // mark v inserted; reset its mind to INF (owner-only write)
        if (lane == L) {
            int slot = (int)(v >> 6);
            if (slot < 64) ins0 |= 1ull << slot; else ins1 |= 1ull << (slot - 64);
            sMind[L * 128 + slot] = 0xFFFF;
        }
        __builtin_amdgcn_wave_barrier();
        // rescan row L -> exact cmin for lane L (R6 idiom: shfl_down + broadcast)
        {
            u32 two = *(const u32*)&sMind[L * 128 + 2 * lane];
            u32 m0 = two & 0xFFFFu, m1 = two >> 16;
            u32 p0 = (m0 << 13) | (u32)(((2 * lane) << 6) | L);
            u32 p1 = (m1 << 13) | (u32)(((2 * lane + 1) << 6) | L);
            u32 pm = p0 < p1 ? p0 : p1;
            #pragma unroll
            for (int off = 32; off; off >>= 1) {
                u32 q = __shfl_down(pm, off, 64);
                pm = q < pm ? q : pm;
            }
            pm = __shfl(pm, 0, 64);
            if (lane == L) cmin = pm;
        }
        // staged chunks: stage 64 entries to scratch, consume via b128 broadcast
        for (u32 base = 0; base < dg; base += 64) {
            u32 ev;
            if (base == 0) ev = ev0;
            else {
                u32 k2 = o + base + (u32)lane;
                ev = (k2 < oe) ? adjG[k2] : 0xFFFFFFFFu;
            }
            scratch[lane] = ev;
            __builtin_amdgcn_wave_barrier();
            u32 cnt = dg - base; if (cnt > 64) cnt = 64;
            const uint4* s4 = (const uint4*)scratch;
            for (u32 c = 0; c < cnt; c += 16) {
                uint4 qa = s4[(c >> 2) + 0];
                uint4 qb = s4[(c >> 2) + 1];
                uint4 qc = s4[(c >> 2) + 2];
                uint4 qd = s4[(c >> 2) + 3];
                u32 ebuf[16] = {qa.x, qa.y, qa.z, qa.w, qb.x, qb.y, qb.z, qb.w,
                                qc.x, qc.y, qc.z, qc.w, qd.x, qd.y, qd.z, qd.w};
                #pragma unroll
                for (int j = 0; j < 16; j++) {
                    u32 e = ebuf[j];
                    if (e != 0xFFFFFFFFu && (int)(e & 63u) == lane) {
                        u32 far = e & 8191u, rk = e >> 13;
                        int slot = (int)(far >> 6);
                        bool isin = (slot < 64) ? (((ins0 >> slot) & 1ull) != 0)
                                                : (((ins1 >> (slot - 64)) & 1ull) != 0);
                        if (!isin) {
                            int loc = lane * 128 + slot;
                            u32 cu = sMind[loc];
                            if (rk < cu) {
                                sMind[loc] = (u16)rk;
                                u32 pk = (rk << 13) | far;
                                if (pk < cmin) cmin = pk;
                            }
                        }
                    }
                }
            }
            __builtin_amdgcn_wave_barrier();
        }
        // pop (R6 idiom)
        u32 p = cmin;
        #pragma unroll
        for (int off = 32; off; off >>= 1) {
            u32 q = __shfl_down(p, off, 64);
            p = q < p ? q : p;
        }
        p = __shfl(p, 0, 64);
        if (p >= INFP) { if (lane == 0) atomicOr(&ctr[2], 2u); break; }
        if (lane == 0) seqv[step] = p;
        v = p & 8191u;
    }
}

// ---------------- gather: deaths = sqrt(d2 of popped rank), clamped ------------
__global__ void gather_kernel(const u32* __restrict__ seqv,
                              const u32* __restrict__ sortedWB,
                              float* __restrict__ out) {
    int s = blockIdx.x * blockDim.x + threadIdx.x;
    if (s < N - 1) {
        u32 p = seqv[s];
        u32 rk = p >> 13;
        if (rk > 8190u) rk = 8190u;   // keep output finite even on upstream failure
        out[2 * s + 1] = sqrtf(__uint_as_float(sortedWB[rk]));
    }
}

extern "C" void kernel_launch(void* const* d_in, const int* in_sizes, int n_in,
                              void* d_out, int out_size, void* d_ws, size_t ws_size,
                              hipStream_t stream) {
    const float* x = (const float*)d_in[0];
    float* out = (float*)d_out;

    char* ws = (char*)d_ws;
    size_t o = 0;
    u64* bestR    = (u64*)(ws + o); o += 8192 * 8;
    u64* bestC    = (u64*)(ws + o); o += 8192 * 8;
    u64* mstKeys  = (u64*)(ws + o); o += 8192 * 8;
    u64* edges    = (u64*)(ws + o); o += (size_t)CAP_E * 8;      // 16 MB
    float* norms  = (float*)(ws + o); o += 8192 * 4;
    u32* sortedWB = (u32*)(ws + o); o += 8192 * 4;
    u32* deg      = (u32*)(ws + o); o += 8192 * 4;
    u32* offs     = (u32*)(ws + o); o += 8200 * 4;
    u32* cur      = (u32*)(ws + o); o += 8192 * 4;
    u32* seqv     = (u32*)(ws + o); o += 8192 * 4;
    u32* adj      = (u32*)(ws + o); o += (size_t)CAP_E * 2 * 4;  // 16 MB
    u16* comp16   = (u16*)(ws + o); o += 8192 * 2;
    u32* ctr      = (u32*)(ws + o); o += 256;
    // total ~33 MB << 256 MiB

    zero_out_kernel<<<(out_size + 255) / 256, 256, 0, stream>>>(out, out_size);
    norms_kernel<<<32, 256, 0, stream>>>(x, norms);
    init_kernel<<<32, 256, 0, stream>>>(bestR, bestC, comp16, deg, ctr);

    for (int r = 0; r < 13; r++) {
        scan_fused<<<dim3(128, 128), 256, 0, stream>>>(x, norms, comp16, bestR, ctr);
        fold_kernel<<<32, 256, 0, stream>>>(bestR, bestC, comp16, ctr);
        merge_kernel<<<1, 1024, 0, stream>>>(comp16, bestC, mstKeys, ctr);
    }

    sort_kernel<<<1, 1024, 0, stream>>>(mstKeys, sortedWB, ctr);
    collect_kernel<<<dim3(128, 128), 256, 0, stream>>>(x, norms, sortedWB, edges, ctr);
    degcnt_kernel<<<512, 256, 0, stream>>>(edges, deg, ctr);
    offs_kernel<<<1, 1024, 0, stream>>>(deg, offs, cur);
    fill_kernel<<<512, 256, 0, stream>>>(edges, cur, adj, ctr);
    gprim_kernel<<<1, 64, 0, stream>>>(offs, adj, seqv, ctr);
    gather_kernel<<<32, 256, 0, stream>>>(seqv, sortedWB, out);
}

// Round 11
// 10217.144 us; speedup vs baseline: 1.3180x; 1.3180x over previous
//
#include <hip/hip_runtime.h>
#include <math.h>

#define N 8192
#define DIM 64
#define CAP_E 2000000

typedef unsigned long long u64;
typedef unsigned int u32;
typedef unsigned short u16;

// ---------------- zero the output buffer (births stay 0) -----------------------
__global__ void zero_out_kernel(float* __restrict__ out, int n) {
    int i = blockIdx.x * blockDim.x + threadIdx.x;
    if (i < n) out[i] = 0.0f;
}

// ---------------- canonical norms: ni = sum fmaf(x_k, x_k) ascending k ---------
__global__ __launch_bounds__(256) void norms_kernel(const float* __restrict__ x,
                                                    float* __restrict__ norms) {
    int i = blockIdx.x * blockDim.x + threadIdx.x;
    const float* row = x + (size_t)i * DIM;
    float acc = 0.f;
    #pragma unroll
    for (int k = 0; k < DIM; k++) { float v = row[k]; acc = __builtin_fmaf(v, v, acc); }
    norms[i] = acc;
}

// ---------------- canonical tile machinery (FROZEN — matches R6 bitwise) -------
__device__ inline void stage_tiles(const float* __restrict__ x, int bi, int bj, int t,
                                   float (*As)[64], float (*Bs)[64]) {
    int r = t >> 2, c0 = (t & 3) * 16;
    const float4* pa = (const float4*)(x + (size_t)(bi * 64 + r) * DIM + c0);
    const float4* pb = (const float4*)(x + (size_t)(bj * 64 + r) * DIM + c0);
    #pragma unroll
    for (int q = 0; q < 4; q++) {
        float4 a = pa[q], b = pb[q];
        int c = c0 + q * 4;
        As[c + 0][r] = a.x; As[c + 1][r] = a.y; As[c + 2][r] = a.z; As[c + 3][r] = a.w;
        Bs[c + 0][r] = b.x; Bs[c + 1][r] = b.y; Bs[c + 2][r] = b.z; Bs[c + 3][r] = b.w;
    }
}

__device__ inline void tile_d2(const float (*As)[64], const float (*Bs)[64],
                               const float ni[4], const float nj[4],
                               int tx, int ty, u32 d2b[4][4]) {
    float acc[4][4] = {};
    #pragma unroll 4
    for (int k = 0; k < 64; k++) {
        float av[4], bv[4];
        #pragma unroll
        for (int r = 0; r < 4; r++) av[r] = As[k][ty * 4 + r];
        #pragma unroll
        for (int c = 0; c < 4; c++) bv[c] = Bs[k][tx * 4 + c];
        #pragma unroll
        for (int r = 0; r < 4; r++)
            #pragma unroll
            for (int c = 0; c < 4; c++)
                acc[r][c] = __builtin_fmaf(av[r], bv[c], acc[r][c]);
    }
    #pragma unroll
    for (int r = 0; r < 4; r++)
        #pragma unroll
        for (int c = 0; c < 4; c++) {
            float d2 = __builtin_fmaf(-2.0f, acc[r][c], ni[r] + nj[c]);
            d2 = d2 < 0.f ? 0.f : d2;
            d2b[r][c] = __float_as_uint(d2);
        }
}

// ---------------- init ---------------------------------------------------------
// ctr[0]=mstCount ctr[1]=done ctr[2]=flag ctr[3]=edgeCount ctr[7]=dummy
__global__ void init_kernel(u64* bestR, u64* bestC, u16* comp16, u32* deg, u32* ctr) {
    int i = blockIdx.x * blockDim.x + threadIdx.x;
    if (i < 8192) { bestR[i] = ~0ull; bestC[i] = ~0ull; comp16[i] = (u16)i; deg[i] = 0; }
    if (i < 8) ctr[i] = 0;
}

__device__ inline u64 shfl_down_u64(u64 p, int off) {
    unsigned hi = (unsigned)(p >> 32), lo = (unsigned)p;
    hi = __shfl_down(hi, off, 64);
    lo = __shfl_down(lo, off, 64);
    return ((u64)hi << 32) | lo;
}

// ---------------- Boruvka fused scan (unchanged from R6) -----------------------
__global__ __launch_bounds__(256) void scan_fused(const float* __restrict__ x,
                                                  const float* __restrict__ norms,
                                                  const u16* __restrict__ comp16,
                                                  u64* __restrict__ bestR,
                                                  const u32* __restrict__ ctr) {
    if (ctr[1]) return;
    int bi = blockIdx.y, bj = blockIdx.x;
    if (bj < bi) return;
    __shared__ float As[64][64], Bs[64][64];
    __shared__ u16 rc[64], cc[64];
    __shared__ u64 rowBest[64], colBest[64];
    int t = threadIdx.x;
    stage_tiles(x, bi, bj, t, As, Bs);
    if (t < 64) {
        rc[t] = comp16[bi * 64 + t];
        cc[t] = comp16[bj * 64 + t];
        rowBest[t] = ~0ull; colBest[t] = ~0ull;
    }
    __syncthreads();
    int tx = t & 15, ty = t >> 4;
    float ni[4], nj[4];
    #pragma unroll
    for (int r = 0; r < 4; r++) ni[r] = norms[bi * 64 + ty * 4 + r];
    #pragma unroll
    for (int c = 0; c < 4; c++) nj[c] = norms[bj * 64 + tx * 4 + c];
    u32 d2b[4][4];
    tile_d2(As, Bs, ni, nj, tx, ty, d2b);

    #pragma unroll
    for (int r = 0; r < 4; r++) {
        u16 rcv = rc[ty * 4 + r];
        int gi = bi * 64 + ty * 4 + r;
        u64 best = ~0ull;
        #pragma unroll
        for (int c = 0; c < 4; c++) {
            if (cc[tx * 4 + c] != rcv) {
                int gj = bj * 64 + tx * 4 + c;
                u32 lo = gi < gj ? (u32)gi : (u32)gj;
                u32 hi = gi < gj ? (u32)gj : (u32)gi;
                u64 key = ((u64)d2b[r][c] << 26) | ((u64)lo << 13) | hi;
                if (key < best) best = key;
            }
        }
        if (best != ~0ull) atomicMin(&rowBest[ty * 4 + r], best);
    }
    #pragma unroll
    for (int c = 0; c < 4; c++) {
        u16 ccv = cc[tx * 4 + c];
        int gj = bj * 64 + tx * 4 + c;
        u64 best = ~0ull;
        #pragma unroll
        for (int r = 0; r < 4; r++) {
            if (rc[ty * 4 + r] != ccv) {
                int gi = bi * 64 + ty * 4 + r;
                u32 lo = gi < gj ? (u32)gi : (u32)gj;
                u32 hi = gi < gj ? (u32)gj : (u32)gi;
                u64 key = ((u64)d2b[r][c] << 26) | ((u64)lo << 13) | hi;
                if (key < best) best = key;
            }
        }
        if (best != ~0ull) atomicMin(&colBest[tx * 4 + c], best);
    }
    __syncthreads();
    if (t < 64) {
        if (rowBest[t] != ~0ull) atomicMin(&bestR[bi * 64 + t], rowBest[t]);
        if (colBest[t] != ~0ull) atomicMin(&bestR[bj * 64 + t], colBest[t]);
    }
}

// ---------------- fold rows -> components --------------------------------------
__global__ void fold_kernel(u64* bestR, u64* bestC, const u16* comp16, const u32* ctr) {
    if (ctr[1]) return;
    int i = blockIdx.x * blockDim.x + threadIdx.x;
    if (i < 8192) {
        u64 k = bestR[i];
        if (k != ~0ull) { atomicMin(&bestC[comp16[i]], k); bestR[i] = ~0ull; }
    }
}

// ---------------- Boruvka merge (unchanged) ------------------------------------
__global__ __launch_bounds__(1024) void merge_kernel(u16* comp16, u64* bestC,
                                                     u64* mstKeys, u32* ctr) {
    __shared__ u16 ping[8192], pong[8192];
    __shared__ unsigned char act[8192];
    __shared__ u32 cnt_s;
    if (ctr[1]) return;
    int t = threadIdx.x;
    if (t == 0) cnt_s = 0;
    for (int c = t; c < 8192; c += 1024) {
        u64 key = bestC[c];
        u16 par = (u16)c;
        if (key != ~0ull) {
            u32 a = (u32)(key >> 13) & 8191u, b = (u32)key & 8191u;
            u16 ca = comp16[a];
            u16 cv = (ca == (u16)c) ? comp16[b] : ca;
            u64 k2 = bestC[cv];
            bool mutual = false;
            if (k2 != ~0ull) {
                u32 a2 = (u32)(k2 >> 13) & 8191u, b2 = (u32)k2 & 8191u;
                u16 ca2 = comp16[a2];
                u16 cv2 = (ca2 == cv) ? comp16[b2] : ca2;
                mutual = (cv2 == (u16)c);
            }
            par = cv;
            if (mutual && (u32)c < (u32)cv) par = (u16)c;
            bool add = (!mutual) || ((u32)c < (u32)cv);
            if (add) {
                u32 idx = atomicAdd(&ctr[0], 1u);
                if (idx < 8192u) mstKeys[idx] = key;
            }
        }
        ping[c] = par;
        act[c] = 0;
    }
    __syncthreads();
    for (int c = t; c < 8192; c += 1024) bestC[c] = ~0ull;
    __syncthreads();
    for (int it = 0; it < 13; it++) {
        for (int c = t; c < 8192; c += 1024) pong[c] = ping[ping[c]];
        __syncthreads();
        for (int c = t; c < 8192; c += 1024) ping[c] = pong[c];
        __syncthreads();
    }
    for (int v = t; v < 8192; v += 1024) {
        u16 nc = ping[comp16[v]];
        comp16[v] = nc;
        act[nc] = 1;
    }
    __syncthreads();
    u32 local = 0;
    for (int c = t; c < 8192; c += 1024) local += act[c];
    atomicAdd(&cnt_s, local);
    __syncthreads();
    if (t == 0 && cnt_s == 1) ctr[1] = 1;
}

// ---------------- bitonic sort -> sorted d2 bit-patterns (unchanged) -----------
__global__ __launch_bounds__(1024) void sort_kernel(const u64* __restrict__ mstKeys,
                                                    u32* __restrict__ sortedWB,
                                                    const u32* __restrict__ ctr) {
    __shared__ u64 keys[8192];
    int t = threadIdx.x;
    u32 m = ctr[0]; if (m > 8191u) m = 8191u;
    for (int i = t; i < 8192; i += 1024) keys[i] = (i < (int)m) ? mstKeys[i] : ~0ull;
    __syncthreads();
    for (u32 k = 2; k <= 8192; k <<= 1)
        for (u32 j = k >> 1; j > 0; j >>= 1) {
            for (int i = t; i < 8192; i += 1024) {
                u32 ixj = (u32)i ^ j;
                if (ixj > (u32)i) {
                    u64 a = keys[i], b = keys[ixj];
                    bool up = ((i & k) == 0);
                    if ((a > b) == up) { keys[i] = b; keys[ixj] = a; }
                }
            }
            __syncthreads();
        }
    for (int i = t; i < 8192; i += 1024)
        sortedWB[i] = (i < 8191) ? (u32)(keys[i] >> 26) : 0xFFFFFFFFu;
}

// ---------------- collect G' (unchanged; rank = lower_bound index) -------------
__global__ __launch_bounds__(256) void collect_kernel(const float* __restrict__ x,
                                                      const float* __restrict__ norms,
                                                      const u32* __restrict__ sortedWB,
                                                      u64* __restrict__ edges,
                                                      u32* __restrict__ ctr) {
    __shared__ float As[64][64], Bs[64][64];
    __shared__ u32 sw[8191];
    int bi = blockIdx.y, bj = blockIdx.x;
    if (bj < bi) return;
    int t = threadIdx.x;
    stage_tiles(x, bi, bj, t, As, Bs);
    for (int i = t; i < 8191; i += 256) sw[i] = sortedWB[i];
    __syncthreads();
    u32 wmin = sw[0], wmax = sw[8190];
    int tx = t & 15, ty = t >> 4;
    float ni[4], nj[4];
    #pragma unroll
    for (int r = 0; r < 4; r++) ni[r] = norms[bi * 64 + ty * 4 + r];
    #pragma unroll
    for (int c = 0; c < 4; c++) nj[c] = norms[bj * 64 + tx * 4 + c];
    u32 d2b[4][4];
    tile_d2(As, Bs, ni, nj, tx, ty, d2b);

    #pragma unroll
    for (int r = 0; r < 4; r++) {
        int gi = bi * 64 + ty * 4 + r;
        #pragma unroll
        for (int c = 0; c < 4; c++) {
            int gj = bj * 64 + tx * 4 + c;
            if (gj <= gi) continue;
            u32 wb = d2b[r][c];
            if (wb < wmin || wb > wmax) continue;
            int lo = 0, hi = 8190;
            while (lo < hi) { int mid = (lo + hi) >> 1; if (sw[mid] < wb) lo = mid + 1; else hi = mid; }
            if (sw[lo] == wb) {
                u32 idx = atomicAdd(&ctr[3], 1u);
                if (idx < CAP_E)
                    edges[idx] = ((u64)(u32)lo << 26) | ((u64)(u32)gi << 13) | (u32)gj;
                else
                    atomicOr(&ctr[2], 16u);
            }
        }
    }
}

// ---------------- degree count (R6) --------------------------------------------
__global__ void degcnt_kernel(const u64* __restrict__ edges, u32* __restrict__ deg,
                              const u32* __restrict__ ctr) {
    u32 m = ctr[3]; if (m > CAP_E) m = CAP_E;
    for (u32 idx = blockIdx.x * 256u + threadIdx.x; idx < m; idx += gridDim.x * 256u) {
        u64 e = edges[idx];
        atomicAdd(&deg[(u32)(e >> 13) & 8191u], 1u);
        atomicAdd(&deg[(u32)e & 8191u], 1u);
    }
}

// ---------------- prefix sum: offs[8193] + cur (R6) ----------------------------
__global__ __launch_bounds__(1024) void offs_kernel(const u32* __restrict__ deg,
                                                    u32* __restrict__ offs,
                                                    u32* __restrict__ cur) {
    __shared__ u32 partial[1024];
    int t = threadIdx.x;
    u32 loc[8], s = 0;
    #pragma unroll
    for (int e = 0; e < 8; e++) { loc[e] = deg[t * 8 + e]; s += loc[e]; }
    partial[t] = s;
    __syncthreads();
    for (int d = 1; d < 1024; d <<= 1) {
        u32 v = (t >= d) ? partial[t - d] : 0;
        __syncthreads();
        partial[t] += v;
        __syncthreads();
    }
    u32 run = t ? partial[t - 1] : 0;
    #pragma unroll
    for (int e = 0; e < 8; e++) { offs[t * 8 + e] = run; cur[t * 8 + e] = run; run += loc[e]; }
    if (t == 1023) offs[8192] = run;
}

// ---------------- fill CSR adjacency: entry = rank(13)<<13 | far(13) (R6) ------
__global__ void fill_kernel(const u64* __restrict__ edges, u32* __restrict__ cur,
                            u32* __restrict__ adj, const u32* __restrict__ ctr) {
    u32 m = ctr[3]; if (m > CAP_E) m = CAP_E;
    for (u32 idx = blockIdx.x * 256u + threadIdx.x; idx < m; idx += gridDim.x * 256u) {
        u64 e = edges[idx];
        u32 rk = (u32)(e >> 26) & 8191u;
        u32 i = (u32)(e >> 13) & 8191u, j = (u32)e & 8191u;
        u32 p1 = atomicAdd(&cur[i], 1u); adj[p1] = (rk << 13) | j;
        u32 p2 = atomicAdd(&cur[j], 1u); adj[p2] = (rk << 13) | i;
    }
}

// ---------------- exact sparse Prim on G' — R6 semantics, batched chunk load ---
// R6-proven invariants: owner-only sMind writes (vertex u owned by lane u&63),
// owner-only cmin maintenance, full rescan of popped vertex's row, SERIAL
// broadcast consume (q < cnt only), shfl_down+broadcast reduces ONLY.
// Latency opts (all individually proven in passing rounds): u32 keys, L2 warm
// pass, batched parallel chunk load (1 global latency instead of dg serial),
// first-chunk load hoisted above the rescan.
__global__ __launch_bounds__(64) void gprim_kernel(const u32* __restrict__ offs,
                                                   const u32* __restrict__ adjG,
                                                   u32* __restrict__ seqv,
                                                   u32* __restrict__ ctr) {
    __shared__ u16 sMind[8192];   // vertex v -> sMind[(v&63)*128 + (v>>6)], 0xFFFF = inf
    __shared__ u32 sOffs[8193];
    __shared__ u32 scratch[64];
    const int lane = threadIdx.x;
    for (int i = lane; i < 8192; i += 64) sMind[i] = 0xFFFF;
    for (int i = lane; i < 8193; i += 64) sOffs[i] = offs[i];
    __syncthreads();

    // warm adj (512 KB window) into this XCD's L2 — read-only, no side effects
    {
        u32 acc = 0;
        const uint4* p4 = (const uint4*)adjG;
        for (int i = lane; i < 32768; i += 64) {
            uint4 q = p4[i];
            acc ^= q.x ^ q.y ^ q.z ^ q.w;
        }
        if (acc == 0xDEADBEEFu) atomicAdd(&ctr[7], 1u);   // keep loads alive
    }

    const u32 INFP = 0xFFFFu << 13;
    u64 ins0 = 0, ins1 = 0;            // inserted bits for this lane's 128 slots
    u32 cmin = 0xFFFFFFFFu;
    u32 v = 0;

    for (int step = 0; step < N - 1; ++step) {
        const int L = (int)(v & 63u);
        u32 o = sOffs[v], oe = sOffs[v + 1];
        u32 dg = oe - o;
        // issue first-chunk adjacency load early (overlaps the rescan below)
        u32 kk = o + (u32)lane;
        u32 ev0 = 0xFFFFFFFFu;
        if (kk < oe) ev0 = adjG[kk];
        // mark v inserted; reset its mind to INF (owner-only write)
        if (lane == L) {
            int slot = (int)(v >> 6);
            if (slot < 64) ins0 |= 1ull << slot; else ins1 |= 1ull << (slot - 64);
            sMind[L * 128 + slot] = 0xFFFF;
        }
        __builtin_amdgcn_wave_barrier();
        // rescan row L -> exact cmin for lane L (R6 idiom: shfl_down + broadcast)
        {
            u32 two = *(const u32*)&sMind[L * 128 + 2 * lane];
            u32 m0 = two & 0xFFFFu, m1 = two >> 16;
            u32 p0 = (m0 << 13) | (u32)(((2 * lane) << 6) | L);
            u32 p1 = (m1 << 13) | (u32)(((2 * lane + 1) << 6) | L);
            u32 pm = p0 < p1 ? p0 : p1;
            #pragma unroll
            for (int off = 32; off; off >>= 1) {
                u32 q = __shfl_down(pm, off, 64);
                pm = q < pm ? q : pm;
            }
            pm = __shfl(pm, 0, 64);
            if (lane == L) cmin = pm;
        }
        // staged chunks: batched parallel load -> serial broadcast consume (R6)
        for (u32 base = 0; base < dg; base += 64) {
            u32 ev;
            if (base == 0) ev = ev0;
            else {
                u32 k2 = o + base + (u32)lane;
                ev = (k2 < oe) ? adjG[k2] : 0xFFFFFFFFu;
            }
            scratch[lane] = ev;
            __builtin_amdgcn_wave_barrier();
            u32 cnt = dg - base; if (cnt > 64) cnt = 64;
            for (u32 q = 0; q < cnt; q++) {
                u32 e = scratch[q];
                u32 far = e & 8191u, rk = e >> 13;
                if ((int)(far & 63u) == lane) {
                    int slot = (int)(far >> 6);
                    bool isin = (slot < 64) ? (((ins0 >> slot) & 1ull) != 0)
                                            : (((ins1 >> (slot - 64)) & 1ull) != 0);
                    if (!isin) {
                        int loc = lane * 128 + slot;
                        u32 cu = sMind[loc];
                        if (rk < cu) {
                            sMind[loc] = (u16)rk;
                            u32 pk = (rk << 13) | far;
                            if (pk < cmin) cmin = pk;
                        }
                    }
                }
            }
            __builtin_amdgcn_wave_barrier();
        }
        // pop (R6 idiom)
        u32 p = cmin;
        #pragma unroll
        for (int off = 32; off; off >>= 1) {
            u32 q = __shfl_down(p, off, 64);
            p = q < p ? q : p;
        }
        p = __shfl(p, 0, 64);
        if (p >= INFP) { if (lane == 0) atomicOr(&ctr[2], 2u); break; }
        if (lane == 0) seqv[step] = p;
        v = p & 8191u;
    }
}

// ---------------- gather: deaths = sqrt(d2 of popped rank), clamped ------------
__global__ void gather_kernel(const u32* __restrict__ seqv,
                              const u32* __restrict__ sortedWB,
                              float* __restrict__ out) {
    int s = blockIdx.x * blockDim.x + threadIdx.x;
    if (s < N - 1) {
        u32 p = seqv[s];
        u32 rk = p >> 13;
        if (rk > 8190u) rk = 8190u;   // keep output finite even on upstream failure
        out[2 * s + 1] = sqrtf(__uint_as_float(sortedWB[rk]));
    }
}

extern "C" void kernel_launch(void* const* d_in, const int* in_sizes, int n_in,
                              void* d_out, int out_size, void* d_ws, size_t ws_size,
                              hipStream_t stream) {
    const float* x = (const float*)d_in[0];
    float* out = (float*)d_out;

    char* ws = (char*)d_ws;
    size_t o = 0;
    u64* bestR    = (u64*)(ws + o); o += 8192 * 8;
    u64* bestC    = (u64*)(ws + o); o += 8192 * 8;
    u64* mstKeys  = (u64*)(ws + o); o += 8192 * 8;
    u64* edges    = (u64*)(ws + o); o += (size_t)CAP_E * 8;      // 16 MB
    float* norms  = (float*)(ws + o); o += 8192 * 4;
    u32* sortedWB = (u32*)(ws + o); o += 8192 * 4;
    u32* deg      = (u32*)(ws + o); o += 8192 * 4;
    u32* offs     = (u32*)(ws + o); o += 8200 * 4;
    u32* cur      = (u32*)(ws + o); o += 8192 * 4;
    u32* seqv     = (u32*)(ws + o); o += 8192 * 4;
    u32* adj      = (u32*)(ws + o); o += (size_t)CAP_E * 2 * 4;  // 16 MB
    u16* comp16   = (u16*)(ws + o); o += 8192 * 2;
    u32* ctr      = (u32*)(ws + o); o += 256;
    // total ~33 MB << 256 MiB

    zero_out_kernel<<<(out_size + 255) / 256, 256, 0, stream>>>(out, out_size);
    norms_kernel<<<32, 256, 0, stream>>>(x, norms);
    init_kernel<<<32, 256, 0, stream>>>(bestR, bestC, comp16, deg, ctr);

    for (int r = 0; r < 13; r++) {
        scan_fused<<<dim3(128, 128), 256, 0, stream>>>(x, norms, comp16, bestR, ctr);
        fold_kernel<<<32, 256, 0, stream>>>(bestR, bestC, comp16, ctr);
        merge_kernel<<<1, 1024, 0, stream>>>(comp16, bestC, mstKeys, ctr);
    }

    sort_kernel<<<1, 1024, 0, stream>>>(mstKeys, sortedWB, ctr);
    collect_kernel<<<dim3(128, 128), 256, 0, stream>>>(x, norms, sortedWB, edges, ctr);
    degcnt_kernel<<<512, 256, 0, stream>>>(edges, deg, ctr);
    offs_kernel<<<1, 1024, 0, stream>>>(deg, offs, cur);
    fill_kernel<<<512, 256, 0, stream>>>(edges, cur, adj, ctr);
    gprim_kernel<<<1, 64, 0, stream>>>(offs, adj, seqv, ctr);
    gather_kernel<<<32, 256, 0, stream>>>(seqv, sortedWB, out);
}